// Round 2
// baseline (210.810 us; speedup 1.0000x reference)
//
#include <hip/hip_runtime.h>
#include <hip/hip_bf16.h>
#include <stdint.h>
#include <stddef.h>

#define T_TOK 2048
#define DDIM  2048
#define FDIM  768
#define NEXP  8
#define NSLOT (T_TOK*2)

typedef __attribute__((ext_vector_type(4))) float  f32x4;
typedef __attribute__((ext_vector_type(8))) short  bf16x8;

// ---- workspace layout (bytes) ----
static constexpr size_t WS_CNT  = 0;                                  // 8 int
static constexpr size_t WS_TOK  = 256;                                // [E][T] int
static constexpr size_t WS_WT   = WS_TOK + (size_t)NEXP*T_TOK*4;      // [E][T] float
static constexpr size_t WS_XB   = WS_WT  + (size_t)NEXP*T_TOK*4;      // [T][D] bf16
static constexpr size_t WS_W1T  = WS_XB  + (size_t)T_TOK*DDIM*2;      // [E][F][D] bf16
static constexpr size_t WS_W3T  = WS_W1T + (size_t)NEXP*FDIM*DDIM*2;  // [E][F][D] bf16
static constexpr size_t WS_W2T  = WS_W3T + (size_t)NEXP*FDIM*DDIM*2;  // [E][D][F] bf16
static constexpr size_t WS_ACT  = WS_W2T + (size_t)NEXP*DDIM*FDIM*2;  // [NSLOT][F] bf16
// end ~90.3 MB

__device__ __forceinline__ void gl_lds16(const void* g, void* l) {
  __builtin_amdgcn_global_load_lds((const __attribute__((address_space(1))) void*)g,
                                   (__attribute__((address_space(3))) void*)l, 16, 0, 0);
}

__device__ __forceinline__ f32x4 mfma_bf16(bf16x8 a, bf16x8 b, f32x4 c) {
  asm("v_mfma_f32_16x16x32_bf16 %0, %1, %2, %0" : "+v"(c) : "v"(a), "v"(b));
  return c;
}

// ---- fused: x fp32 -> bf16 cast + router (logits, top-2, renorm, scatter) ----
__global__ __launch_bounds__(256) void k_router(const float* __restrict__ x,
                                                const float* __restrict__ gw,
                                                __hip_bfloat16* __restrict__ xb,
                                                int* __restrict__ cnt,
                                                int* __restrict__ tok,
                                                float* __restrict__ wt) {
  int wave = threadIdx.x >> 6, lane = threadIdx.x & 63;
  int t = blockIdx.x*4 + wave;
  const float* xr = x + (size_t)t*DDIM;
  float acc[NEXP] = {0.f,0.f,0.f,0.f,0.f,0.f,0.f,0.f};
#pragma unroll
  for (int i = 0; i < DDIM/256; i++) {
    int d0 = i*256 + lane*4;
    union { float4 v; float f[4]; } xv;
    xv.v = *(const float4*)(xr + d0);
    union { __hip_bfloat16 h[4]; uint2 u; } pk;
#pragma unroll
    for (int j = 0; j < 4; j++) {
      float xvj = xv.f[j];
      pk.h[j] = __float2bfloat16(xvj);
      float4 g0 = *(const float4*)(gw + (size_t)(d0+j)*8);
      float4 g1 = *(const float4*)(gw + (size_t)(d0+j)*8 + 4);
      acc[0] += xvj*g0.x; acc[1] += xvj*g0.y; acc[2] += xvj*g0.z; acc[3] += xvj*g0.w;
      acc[4] += xvj*g1.x; acc[5] += xvj*g1.y; acc[6] += xvj*g1.z; acc[7] += xvj*g1.w;
    }
    *(uint2*)(xb + (size_t)t*DDIM + d0) = pk.u;
  }
#pragma unroll
  for (int off = 32; off >= 1; off >>= 1) {
#pragma unroll
    for (int e = 0; e < NEXP; e++) acc[e] += __shfl_xor(acc[e], off, 64);
  }
  if (lane == 0) {
    int i1 = 0; float m1 = acc[0];
#pragma unroll
    for (int e = 1; e < NEXP; e++) if (acc[e] > m1) { m1 = acc[e]; i1 = e; }
    int i2 = -1; float m2 = -1e30f;
#pragma unroll
    for (int e = 0; e < NEXP; e++) if (e != i1 && acc[e] > m2) { m2 = acc[e]; i2 = e; }
    float r  = expf(m2 - m1);          // p2/p1
    float wa = 1.f/(1.f + r);
    float wb = r/(1.f + r);
    int p1 = atomicAdd(&cnt[i1], 1);
    tok[i1*T_TOK + p1] = t;  wt[i1*T_TOK + p1] = wa;
    int p2 = atomicAdd(&cnt[i2], 1);
    tok[i2*T_TOK + p2] = t;  wt[i2*T_TOK + p2] = wb;
  }
}

// ---- [E][R][C] fp32 -> [E][C][R] bf16, two matrices fused (z<8: pair0, else pair1)
// 64(r) x 32(c) tiles; packed 2-element (4B) transposed stores.
__global__ __launch_bounds__(256) void k_tc(const float* __restrict__ srcA,
                                            __hip_bfloat16* __restrict__ dstA,
                                            const float* __restrict__ srcB,
                                            __hip_bfloat16* __restrict__ dstB,
                                            int R, int C) {
  __shared__ float tile[64][33];
  int z = blockIdx.z;
  const float* s = (z < 8 ? srcA : srcB) + (size_t)(z & 7)*R*C;
  __hip_bfloat16* d = (z < 8 ? dstA : dstB) + (size_t)(z & 7)*C*R;
  int c0 = blockIdx.x*32, r0 = blockIdx.y*64;
  int tx = threadIdx.x, ty = threadIdx.y;
#pragma unroll
  for (int i = 0; i < 64; i += 8)
    tile[ty+i][tx] = s[(size_t)(r0+ty+i)*C + (c0+tx)];
  __syncthreads();
#pragma unroll
  for (int i = 0; i < 32; i += 8) {
    int c = c0 + ty + i;
    union { __hip_bfloat16 h[2]; unsigned int u; } pk;
    pk.h[0] = __float2bfloat16(tile[2*tx][ty+i]);
    pk.h[1] = __float2bfloat16(tile[2*tx+1][ty+i]);
    *(unsigned int*)(d + (size_t)c*R + r0 + 2*tx) = pk.u;
  }
}

// ---- phase 1: per-expert grouped GEMM: g = Xe@W1, u = Xe@W3, act = silu(g)*u
// BM=64 slots, BN=128 f, BK=64. 4 waves in 2x2; each wave 32x64 for BOTH gemms.
__global__ __launch_bounds__(256,3) void k_ffn1(
    const __hip_bfloat16* __restrict__ xb,
    const __hip_bfloat16* __restrict__ w1t,   // [E][F][D]
    const __hip_bfloat16* __restrict__ w3t,   // [E][F][D]
    const int* __restrict__ cnt,
    const int* __restrict__ tok,
    __hip_bfloat16* __restrict__ act) {       // [NSLOT][F]
  int e  = blockIdx.z;
  int ne = cnt[e];
  int m0 = blockIdx.y * 64;
  if (m0 >= ne) return;
  int n0 = blockIdx.x * 128;
  int tid = threadIdx.x, wave = tid >> 6, lane = tid & 63;

  __shared__ __hip_bfloat16 sA[64*64], sB1[128*64], sB3[128*64];

  // staging: per call, 256 threads cover 32 rows (8 chunks of 16B each).
  // LDS dest linear (wave-uniform base + lane*16); global source pre-XOR-swizzled.
  const __hip_bfloat16 *aptr[2], *b1p[4], *b3p[4];
  int ldsA[2], ldsB[4];
#pragma unroll
  for (int c = 0; c < 2; c++) {
    int r  = c*32 + wave*8 + (lane>>3);
    int kb = ((lane&7)*16) ^ ((r&7)<<4);
    int slot = m0 + r; if (slot >= ne) slot = ne - 1;
    int t = tok[e*T_TOK + slot];
    aptr[c] = xb + (size_t)t*DDIM + (kb>>1);
    ldsA[c] = (c*32 + wave*8)*128;
  }
#pragma unroll
  for (int c = 0; c < 4; c++) {
    int r  = c*32 + wave*8 + (lane>>3);
    int kb = ((lane&7)*16) ^ ((r&7)<<4);
    b1p[c] = w1t + ((size_t)e*FDIM + n0 + r)*DDIM + (kb>>1);
    b3p[c] = w3t + ((size_t)e*FDIM + n0 + r)*DDIM + (kb>>1);
    ldsB[c] = (c*32 + wave*8)*128;
  }

  f32x4 accg[2][4], accu[2][4];
#pragma unroll
  for (int a = 0; a < 2; a++)
#pragma unroll
    for (int b = 0; b < 4; b++) {
      accg[a][b] = (f32x4){0.f,0.f,0.f,0.f};
      accu[a][b] = (f32x4){0.f,0.f,0.f,0.f};
    }

  int wr = wave >> 1, wc = wave & 1;

  for (int kt = 0; kt < DDIM/64; ++kt) {
#pragma unroll
    for (int c = 0; c < 2; c++) gl_lds16(aptr[c] + kt*64, (char*)sA  + ldsA[c]);
#pragma unroll
    for (int c = 0; c < 4; c++) gl_lds16(b1p[c]  + kt*64, (char*)sB1 + ldsB[c]);
#pragma unroll
    for (int c = 0; c < 4; c++) gl_lds16(b3p[c]  + kt*64, (char*)sB3 + ldsB[c]);
    __syncthreads();
#pragma unroll
    for (int ks = 0; ks < 2; ks++) {
      int q = ks*64 + ((lane>>4)<<4);
      bf16x8 a_[2], b1_[4], b3_[4];
#pragma unroll
      for (int mf = 0; mf < 2; mf++) {
        int r = wr*32 + mf*16 + (lane&15);
        a_[mf] = *(const bf16x8*)((const char*)sA + r*128 + (q ^ ((r&7)<<4)));
      }
#pragma unroll
      for (int nf = 0; nf < 4; nf++) {
        int r = wc*64 + nf*16 + (lane&15);
        int off = r*128 + (q ^ ((r&7)<<4));
        b1_[nf] = *(const bf16x8*)((const char*)sB1 + off);
        b3_[nf] = *(const bf16x8*)((const char*)sB3 + off);
      }
#pragma unroll
      for (int mf = 0; mf < 2; mf++)
#pragma unroll
        for (int nf = 0; nf < 4; nf++) {
          accg[mf][nf] = mfma_bf16(a_[mf], b1_[nf], accg[mf][nf]);
          accu[mf][nf] = mfma_bf16(a_[mf], b3_[nf], accu[mf][nf]);
        }
    }
    __syncthreads();
  }

  int be = 0;
#pragma unroll
  for (int i = 0; i < NEXP; i++) if (i < e) be += cnt[i];
#pragma unroll
  for (int mf = 0; mf < 2; mf++)
#pragma unroll
    for (int nf = 0; nf < 4; nf++)
#pragma unroll
      for (int j = 0; j < 4; j++) {
        int slot = m0 + wr*32 + mf*16 + (lane>>4)*4 + j;  // C/D: row=(lane>>4)*4+j
        if (slot < ne) {
          int f = n0 + wc*64 + nf*16 + (lane&15);         // C/D: col=lane&15
          float g = accg[mf][nf][j], u = accu[mf][nf][j];
          float s = g / (1.f + __expf(-g));
          act[(size_t)(be+slot)*FDIM + f] = __float2bfloat16(s*u);
        }
      }
}

// ---- phase 2: Y = act @ W2, scaled scatter-add into y. BM=64, BN=128, BK=64.
__global__ __launch_bounds__(256,4) void k_ffn2(
    const __hip_bfloat16* __restrict__ act,   // [NSLOT][F]
    const __hip_bfloat16* __restrict__ w2t,   // [E][D][F]
    const int* __restrict__ cnt,
    const int* __restrict__ tok, const float* __restrict__ wt,
    float* __restrict__ y) {
  int e  = blockIdx.z;
  int ne = cnt[e];
  int m0 = blockIdx.y * 64;
  if (m0 >= ne) return;
  int n0 = blockIdx.x * 128;
  int tid = threadIdx.x, wave = tid >> 6, lane = tid & 63;
  int be = 0;
#pragma unroll
  for (int i = 0; i < NEXP; i++) if (i < e) be += cnt[i];

  __shared__ __hip_bfloat16 sA[64*64], sB[128*64];

  const __hip_bfloat16 *aptr[2], *bp[4];
  int ldsA[2], ldsB[4];
#pragma unroll
  for (int c = 0; c < 2; c++) {
    int r  = c*32 + wave*8 + (lane>>3);
    int kb = ((lane&7)*16) ^ ((r&7)<<4);
    int slot = m0 + r; if (slot >= ne) slot = ne - 1;
    aptr[c] = act + (size_t)(be+slot)*FDIM + (kb>>1);
    ldsA[c] = (c*32 + wave*8)*128;
  }
#pragma unroll
  for (int c = 0; c < 4; c++) {
    int r  = c*32 + wave*8 + (lane>>3);
    int kb = ((lane&7)*16) ^ ((r&7)<<4);
    bp[c]  = w2t + ((size_t)e*DDIM + n0 + r)*FDIM + (kb>>1);
    ldsB[c] = (c*32 + wave*8)*128;
  }

  f32x4 acc[2][4];
#pragma unroll
  for (int a = 0; a < 2; a++)
#pragma unroll
    for (int b = 0; b < 4; b++) acc[a][b] = (f32x4){0.f,0.f,0.f,0.f};

  int wr = wave >> 1, wc = wave & 1;

  for (int kt = 0; kt < FDIM/64; ++kt) {
#pragma unroll
    for (int c = 0; c < 2; c++) gl_lds16(aptr[c] + kt*64, (char*)sA + ldsA[c]);
#pragma unroll
    for (int c = 0; c < 4; c++) gl_lds16(bp[c]   + kt*64, (char*)sB + ldsB[c]);
    __syncthreads();
#pragma unroll
    for (int ks = 0; ks < 2; ks++) {
      int q = ks*64 + ((lane>>4)<<4);
      bf16x8 a_[2], b_[4];
#pragma unroll
      for (int mf = 0; mf < 2; mf++) {
        int r = wr*32 + mf*16 + (lane&15);
        a_[mf] = *(const bf16x8*)((const char*)sA + r*128 + (q ^ ((r&7)<<4)));
      }
#pragma unroll
      for (int nf = 0; nf < 4; nf++) {
        int r = wc*64 + nf*16 + (lane&15);
        b_[nf] = *(const bf16x8*)((const char*)sB + r*128 + (q ^ ((r&7)<<4)));
      }
#pragma unroll
      for (int mf = 0; mf < 2; mf++)
#pragma unroll
        for (int nf = 0; nf < 4; nf++)
          acc[mf][nf] = mfma_bf16(a_[mf], b_[nf], acc[mf][nf]);
    }
    __syncthreads();
  }

#pragma unroll
  for (int mf = 0; mf < 2; mf++)
#pragma unroll
    for (int nf = 0; nf < 4; nf++)
#pragma unroll
      for (int j = 0; j < 4; j++) {
        int slot = m0 + wr*32 + mf*16 + (lane>>4)*4 + j;
        if (slot < ne) {
          int d  = n0 + wc*64 + nf*16 + (lane&15);
          int t  = tok[e*T_TOK + slot];
          float w = wt[e*T_TOK + slot];
          unsafeAtomicAdd(y + (size_t)t*DDIM + d, w*acc[mf][nf][j]);
        }
      }
}

extern "C" void kernel_launch(void* const* d_in, const int* in_sizes, int n_in,
                              void* d_out, int out_size, void* d_ws, size_t ws_size,
                              hipStream_t stream) {
  const float* x  = (const float*)d_in[0];
  const float* gw = (const float*)d_in[1];
  const float* w1 = (const float*)d_in[2];
  const float* w2 = (const float*)d_in[3];
  const float* w3 = (const float*)d_in[4];
  float* y = (float*)d_out;
  char* ws = (char*)d_ws;

  int*   cnt  = (int*)  (ws + WS_CNT);
  int*   tok  = (int*)  (ws + WS_TOK);
  float* wtb  = (float*)(ws + WS_WT);
  __hip_bfloat16* xb   = (__hip_bfloat16*)(ws + WS_XB);
  __hip_bfloat16* w1t  = (__hip_bfloat16*)(ws + WS_W1T);
  __hip_bfloat16* w3t  = (__hip_bfloat16*)(ws + WS_W3T);
  __hip_bfloat16* w2t  = (__hip_bfloat16*)(ws + WS_W2T);
  __hip_bfloat16* actb = (__hip_bfloat16*)(ws + WS_ACT);

  hipMemsetAsync(ws + WS_CNT, 0, 256, stream);
  hipMemsetAsync(d_out, 0, (size_t)out_size * sizeof(float), stream);

  k_router<<<T_TOK/4, 256, 0, stream>>>(x, gw, xb, cnt, tok, wtb);

  dim3 tb(32, 8);
  // w1 [E][D][F] -> [E][F][D], w3 same (fused, z=16)
  k_tc<<<dim3(FDIM/32, DDIM/64, 16), tb, 0, stream>>>(w1, w1t, w3, w3t, DDIM, FDIM);
  // w2 [E][F][D] -> [E][D][F]
  k_tc<<<dim3(DDIM/32, FDIM/64, 8), tb, 0, stream>>>(w2, w2t, w2, w2t, FDIM, DDIM);

  k_ffn1<<<dim3(FDIM/128, T_TOK/64, NEXP), 256, 0, stream>>>(xb, w1t, w3t, cnt, tok, actb);
  k_ffn2<<<dim3(DDIM/128, T_TOK/64, NEXP), 256, 0, stream>>>(actb, w2t, cnt, tok, wtb, y);
}

// Round 3
// 200.237 us; speedup vs baseline: 1.0528x; 1.0528x over previous
//
#include <hip/hip_runtime.h>
#include <hip/hip_bf16.h>
#include <stdint.h>
#include <stddef.h>

#define T_TOK 2048
#define DDIM  2048
#define FDIM  768
#define NEXP  8
#define NSLOT (T_TOK*2)

typedef __attribute__((ext_vector_type(4))) float  f32x4;
typedef __attribute__((ext_vector_type(8))) short  bf16x8;

// ---- workspace layout (bytes) ----
static constexpr size_t WS_CNT  = 0;                                  // 8 int
static constexpr size_t WS_TOK  = 256;                                // [E][T] int
static constexpr size_t WS_WT   = WS_TOK + (size_t)NEXP*T_TOK*4;      // [E][T] float
static constexpr size_t WS_XB   = WS_WT  + (size_t)NEXP*T_TOK*4;      // [T][D] bf16
static constexpr size_t WS_W1T  = WS_XB  + (size_t)T_TOK*DDIM*2;      // [E][F][D] bf16
static constexpr size_t WS_W3T  = WS_W1T + (size_t)NEXP*FDIM*DDIM*2;  // [E][F][D] bf16
static constexpr size_t WS_W2T  = WS_W3T + (size_t)NEXP*FDIM*DDIM*2;  // [E][D][F] bf16
static constexpr size_t WS_ACT  = WS_W2T + (size_t)NEXP*DDIM*FDIM*2;  // [NSLOT][F] bf16
// end ~90.3 MB

__device__ __forceinline__ void gl_lds16(const void* g, void* l) {
  __builtin_amdgcn_global_load_lds((const __attribute__((address_space(1))) void*)g,
                                   (__attribute__((address_space(3))) void*)l, 16, 0, 0);
}

__device__ __forceinline__ f32x4 mfma_bf16(bf16x8 a, bf16x8 b, f32x4 c) {
  asm("v_mfma_f32_16x16x32_bf16 %0, %1, %2, %0" : "+v"(c) : "v"(a), "v"(b));
  return c;
}

// ---- fused cast + router: one block per token, 256 threads.
// Thread owns 8 consecutive d's: independent loads, short chains, 32 waves/CU TLP.
__global__ __launch_bounds__(256) void k_router(const float* __restrict__ x,
                                                const float* __restrict__ gw,
                                                __hip_bfloat16* __restrict__ xb,
                                                int* __restrict__ cnt,
                                                int* __restrict__ tok,
                                                float* __restrict__ wt) {
  int t = blockIdx.x;
  int tid = threadIdx.x, lane = tid & 63, wave = tid >> 6;
  const float* xr = x + (size_t)t*DDIM;
  float4 x0 = *(const float4*)(xr + tid*8);
  float4 x1 = *(const float4*)(xr + tid*8 + 4);
  float xs[8] = {x0.x,x0.y,x0.z,x0.w,x1.x,x1.y,x1.z,x1.w};
  union { __hip_bfloat16 h[8]; int4 v; } pk;
  float acc[NEXP] = {0.f,0.f,0.f,0.f,0.f,0.f,0.f,0.f};
#pragma unroll
  for (int j = 0; j < 8; j++) {
    pk.h[j] = __float2bfloat16(xs[j]);
    float4 g0 = *(const float4*)(gw + (size_t)(tid*8+j)*8);
    float4 g1 = *(const float4*)(gw + (size_t)(tid*8+j)*8 + 4);
    acc[0] += xs[j]*g0.x; acc[1] += xs[j]*g0.y; acc[2] += xs[j]*g0.z; acc[3] += xs[j]*g0.w;
    acc[4] += xs[j]*g1.x; acc[5] += xs[j]*g1.y; acc[6] += xs[j]*g1.z; acc[7] += xs[j]*g1.w;
  }
  *(int4*)(xb + (size_t)t*DDIM + tid*8) = pk.v;
#pragma unroll
  for (int off = 32; off >= 1; off >>= 1) {
#pragma unroll
    for (int e = 0; e < NEXP; e++) acc[e] += __shfl_xor(acc[e], off, 64);
  }
  __shared__ float red[4][NEXP];
  if (lane == 0) {
#pragma unroll
    for (int e = 0; e < NEXP; e++) red[wave][e] = acc[e];
  }
  __syncthreads();
  if (tid == 0) {
    float lg[NEXP];
#pragma unroll
    for (int e = 0; e < NEXP; e++) lg[e] = red[0][e] + red[1][e] + red[2][e] + red[3][e];
    int i1 = 0; float m1 = lg[0];
#pragma unroll
    for (int e = 1; e < NEXP; e++) if (lg[e] > m1) { m1 = lg[e]; i1 = e; }
    int i2 = -1; float m2 = -1e30f;
#pragma unroll
    for (int e = 0; e < NEXP; e++) if (e != i1 && lg[e] > m2) { m2 = lg[e]; i2 = e; }
    float r  = expf(m2 - m1);          // p2/p1
    float wa = 1.f/(1.f + r);
    float wb = r/(1.f + r);
    int p1 = atomicAdd(&cnt[i1], 1);
    tok[i1*T_TOK + p1] = t;  wt[i1*T_TOK + p1] = wa;
    int p2 = atomicAdd(&cnt[i2], 1);
    tok[i2*T_TOK + p2] = t;  wt[i2*T_TOK + p2] = wb;
  }
}

// ---- [E][R][C] fp32 -> [E][C][R] bf16, two matrices fused (z<8: pair0, else pair1)
// 64(r) x 32(c) tiles; 16B packed transposed stores (8 bf16 per thread).
__global__ __launch_bounds__(256) void k_tc(const float* __restrict__ srcA,
                                            __hip_bfloat16* __restrict__ dstA,
                                            const float* __restrict__ srcB,
                                            __hip_bfloat16* __restrict__ dstB,
                                            int R, int C) {
  __shared__ float tile[64][33];
  int z = blockIdx.z;
  const float* s = (z < 8 ? srcA : srcB) + (size_t)(z & 7)*R*C;
  __hip_bfloat16* d = (z < 8 ? dstA : dstB) + (size_t)(z & 7)*C*R;
  int c0 = blockIdx.x*32, r0 = blockIdx.y*64;
  int tx = threadIdx.x & 31, ty = threadIdx.x >> 5;
#pragma unroll
  for (int i = 0; i < 64; i += 8)
    tile[ty+i][tx] = s[(size_t)(r0+ty+i)*C + (c0+tx)];
  __syncthreads();
  int c  = threadIdx.x >> 3;     // 0..31
  int rg = threadIdx.x & 7;      // 0..7  -> rows rg*8..rg*8+8
  union { __hip_bfloat16 h[8]; int4 v; } pk;
#pragma unroll
  for (int j = 0; j < 8; j++) pk.h[j] = __float2bfloat16(tile[rg*8+j][c]);
  *(int4*)(d + (size_t)(c0+c)*R + r0 + rg*8) = pk.v;
}

// ---- phase 1: g = Xe@W1, u = Xe@W3, act = silu(g)*u
// BM=64, BN=128, BK=64; 4 waves 2x2; double-buffered LDS, 2-phase prefetch.
__global__ __launch_bounds__(256,2) void k_ffn1(
    const __hip_bfloat16* __restrict__ xb,
    const __hip_bfloat16* __restrict__ w1t,   // [E][F][D]
    const __hip_bfloat16* __restrict__ w3t,   // [E][F][D]
    const int* __restrict__ cnt,
    const int* __restrict__ tok,
    __hip_bfloat16* __restrict__ act) {       // [NSLOT][F]
  int e  = blockIdx.z;
  int ne = cnt[e];
  int m0 = blockIdx.y * 64;
  if (m0 >= ne) return;
  int n0 = blockIdx.x * 128;
  int tid = threadIdx.x, wave = tid >> 6, lane = tid & 63;

  __shared__ __hip_bfloat16 sA[2][64*64], sB1[2][128*64], sB3[2][128*64]; // 80 KB

  const __hip_bfloat16 *aptr[2], *b1p[4], *b3p[4];
  int ldsA[2], ldsB[4];
#pragma unroll
  for (int c = 0; c < 2; c++) {
    int r  = c*32 + wave*8 + (lane>>3);
    int kb = ((lane&7)*16) ^ ((r&7)<<4);
    int slot = m0 + r; if (slot >= ne) slot = ne - 1;
    int t = tok[e*T_TOK + slot];
    aptr[c] = xb + (size_t)t*DDIM + (kb>>1);
    ldsA[c] = (c*32 + wave*8)*128;
  }
#pragma unroll
  for (int c = 0; c < 4; c++) {
    int r  = c*32 + wave*8 + (lane>>3);
    int kb = ((lane&7)*16) ^ ((r&7)<<4);
    b1p[c] = w1t + ((size_t)e*FDIM + n0 + r)*DDIM + (kb>>1);
    b3p[c] = w3t + ((size_t)e*FDIM + n0 + r)*DDIM + (kb>>1);
    ldsB[c] = (c*32 + wave*8)*128;
  }

  f32x4 accg[2][4], accu[2][4];
#pragma unroll
  for (int a = 0; a < 2; a++)
#pragma unroll
    for (int b = 0; b < 4; b++) {
      accg[a][b] = (f32x4){0.f,0.f,0.f,0.f};
      accu[a][b] = (f32x4){0.f,0.f,0.f,0.f};
    }

  int wr = wave >> 1, wc = wave & 1;

#define FFN1_STAGE(B, KT) do { \
  _Pragma("unroll") for (int c = 0; c < 2; c++) \
    gl_lds16(aptr[c] + (KT)*64, (char*)&sA[B][0]  + ldsA[c]); \
  _Pragma("unroll") for (int c = 0; c < 4; c++) { \
    gl_lds16(b1p[c]  + (KT)*64, (char*)&sB1[B][0] + ldsB[c]); \
    gl_lds16(b3p[c]  + (KT)*64, (char*)&sB3[B][0] + ldsB[c]); } \
} while (0)

#define FFN1_COMP(B) do { \
  _Pragma("unroll") for (int ks = 0; ks < 2; ks++) { \
    int q = ks*64 + ((lane>>4)<<4); \
    bf16x8 a_[2], b1_[4], b3_[4]; \
    _Pragma("unroll") for (int mf = 0; mf < 2; mf++) { \
      int r = wr*32 + mf*16 + (lane&15); \
      a_[mf] = *(const bf16x8*)((const char*)&sA[B][0] + r*128 + (q ^ ((r&7)<<4))); } \
    _Pragma("unroll") for (int nf = 0; nf < 4; nf++) { \
      int r = wc*64 + nf*16 + (lane&15); \
      int off = r*128 + (q ^ ((r&7)<<4)); \
      b1_[nf] = *(const bf16x8*)((const char*)&sB1[B][0] + off); \
      b3_[nf] = *(const bf16x8*)((const char*)&sB3[B][0] + off); } \
    _Pragma("unroll") for (int mf = 0; mf < 2; mf++) \
      _Pragma("unroll") for (int nf = 0; nf < 4; nf++) { \
        accg[mf][nf] = mfma_bf16(a_[mf], b1_[nf], accg[mf][nf]); \
        accu[mf][nf] = mfma_bf16(a_[mf], b3_[nf], accu[mf][nf]); } \
  } \
} while (0)

  const int NK = DDIM/64;   // 32, even
  FFN1_STAGE(0, 0);
  __syncthreads();
  for (int kt = 0; kt < NK; kt += 2) {
    FFN1_STAGE(1, kt+1);
    FFN1_COMP(0);
    __syncthreads();
    if (kt + 2 < NK) FFN1_STAGE(0, kt+2);
    FFN1_COMP(1);
    __syncthreads();
  }

  int be = 0;
#pragma unroll
  for (int i = 0; i < NEXP; i++) if (i < e) be += cnt[i];
#pragma unroll
  for (int mf = 0; mf < 2; mf++)
#pragma unroll
    for (int nf = 0; nf < 4; nf++)
#pragma unroll
      for (int j = 0; j < 4; j++) {
        int slot = m0 + wr*32 + mf*16 + (lane>>4)*4 + j;  // C/D: row=(lane>>4)*4+j
        if (slot < ne) {
          int f = n0 + wc*64 + nf*16 + (lane&15);         // C/D: col=lane&15
          float g = accg[mf][nf][j], u = accu[mf][nf][j];
          float s = g / (1.f + __expf(-g));
          act[(size_t)(be+slot)*FDIM + f] = __float2bfloat16(s*u);
        }
      }
}

// ---- phase 2: Y = act @ W2, scaled scatter-add. BM=64, BN=128, BK=64, dbuf.
__global__ __launch_bounds__(256,3) void k_ffn2(
    const __hip_bfloat16* __restrict__ act,   // [NSLOT][F]
    const __hip_bfloat16* __restrict__ w2t,   // [E][D][F]
    const int* __restrict__ cnt,
    const int* __restrict__ tok, const float* __restrict__ wt,
    float* __restrict__ y) {
  int e  = blockIdx.z;
  int ne = cnt[e];
  int m0 = blockIdx.y * 64;
  if (m0 >= ne) return;
  int n0 = blockIdx.x * 128;
  int tid = threadIdx.x, wave = tid >> 6, lane = tid & 63;
  int be = 0;
#pragma unroll
  for (int i = 0; i < NEXP; i++) if (i < e) be += cnt[i];

  __shared__ __hip_bfloat16 sA[2][64*64], sB[2][128*64];  // 48 KB

  const __hip_bfloat16 *aptr[2], *bp[4];
  int ldsA[2], ldsB[4];
#pragma unroll
  for (int c = 0; c < 2; c++) {
    int r  = c*32 + wave*8 + (lane>>3);
    int kb = ((lane&7)*16) ^ ((r&7)<<4);
    int slot = m0 + r; if (slot >= ne) slot = ne - 1;
    aptr[c] = act + (size_t)(be+slot)*FDIM + (kb>>1);
    ldsA[c] = (c*32 + wave*8)*128;
  }
#pragma unroll
  for (int c = 0; c < 4; c++) {
    int r  = c*32 + wave*8 + (lane>>3);
    int kb = ((lane&7)*16) ^ ((r&7)<<4);
    bp[c]  = w2t + ((size_t)e*DDIM + n0 + r)*FDIM + (kb>>1);
    ldsB[c] = (c*32 + wave*8)*128;
  }

  f32x4 acc[2][4];
#pragma unroll
  for (int a = 0; a < 2; a++)
#pragma unroll
    for (int b = 0; b < 4; b++) acc[a][b] = (f32x4){0.f,0.f,0.f,0.f};

  int wr = wave >> 1, wc = wave & 1;

#define FFN2_STAGE(B, KT) do { \
  _Pragma("unroll") for (int c = 0; c < 2; c++) \
    gl_lds16(aptr[c] + (KT)*64, (char*)&sA[B][0] + ldsA[c]); \
  _Pragma("unroll") for (int c = 0; c < 4; c++) \
    gl_lds16(bp[c]   + (KT)*64, (char*)&sB[B][0] + ldsB[c]); \
} while (0)

#define FFN2_COMP(B) do { \
  _Pragma("unroll") for (int ks = 0; ks < 2; ks++) { \
    int q = ks*64 + ((lane>>4)<<4); \
    bf16x8 a_[2], b_[4]; \
    _Pragma("unroll") for (int mf = 0; mf < 2; mf++) { \
      int r = wr*32 + mf*16 + (lane&15); \
      a_[mf] = *(const bf16x8*)((const char*)&sA[B][0] + r*128 + (q ^ ((r&7)<<4))); } \
    _Pragma("unroll") for (int nf = 0; nf < 4; nf++) { \
      int r = wc*64 + nf*16 + (lane&15); \
      b_[nf] = *(const bf16x8*)((const char*)&sB[B][0] + r*128 + (q ^ ((r&7)<<4))); } \
    _Pragma("unroll") for (int mf = 0; mf < 2; mf++) \
      _Pragma("unroll") for (int nf = 0; nf < 4; nf++) \
        acc[mf][nf] = mfma_bf16(a_[mf], b_[nf], acc[mf][nf]); \
  } \
} while (0)

  const int NK = FDIM/64;   // 12, even
  FFN2_STAGE(0, 0);
  __syncthreads();
  for (int kt = 0; kt < NK; kt += 2) {
    FFN2_STAGE(1, kt+1);
    FFN2_COMP(0);
    __syncthreads();
    if (kt + 2 < NK) FFN2_STAGE(0, kt+2);
    FFN2_COMP(1);
    __syncthreads();
  }

#pragma unroll
  for (int mf = 0; mf < 2; mf++)
#pragma unroll
    for (int nf = 0; nf < 4; nf++)
#pragma unroll
      for (int j = 0; j < 4; j++) {
        int slot = m0 + wr*32 + mf*16 + (lane>>4)*4 + j;
        if (slot < ne) {
          int d  = n0 + wc*64 + nf*16 + (lane&15);
          int t  = tok[e*T_TOK + slot];
          float w = wt[e*T_TOK + slot];
          unsafeAtomicAdd(y + (size_t)t*DDIM + d, w*acc[mf][nf][j]);
        }
      }
}

extern "C" void kernel_launch(void* const* d_in, const int* in_sizes, int n_in,
                              void* d_out, int out_size, void* d_ws, size_t ws_size,
                              hipStream_t stream) {
  const float* x  = (const float*)d_in[0];
  const float* gw = (const float*)d_in[1];
  const float* w1 = (const float*)d_in[2];
  const float* w2 = (const float*)d_in[3];
  const float* w3 = (const float*)d_in[4];
  float* y = (float*)d_out;
  char* ws = (char*)d_ws;

  int*   cnt  = (int*)  (ws + WS_CNT);
  int*   tok  = (int*)  (ws + WS_TOK);
  float* wtb  = (float*)(ws + WS_WT);
  __hip_bfloat16* xb   = (__hip_bfloat16*)(ws + WS_XB);
  __hip_bfloat16* w1t  = (__hip_bfloat16*)(ws + WS_W1T);
  __hip_bfloat16* w3t  = (__hip_bfloat16*)(ws + WS_W3T);
  __hip_bfloat16* w2t  = (__hip_bfloat16*)(ws + WS_W2T);
  __hip_bfloat16* actb = (__hip_bfloat16*)(ws + WS_ACT);

  hipMemsetAsync(ws + WS_CNT, 0, 256, stream);
  hipMemsetAsync(d_out, 0, (size_t)out_size * sizeof(float), stream);

  k_router<<<T_TOK, 256, 0, stream>>>(x, gw, xb, cnt, tok, wtb);

  dim3 tb(256);
  // w1 [E][D][F] -> [E][F][D], w3 same (fused, z=16)
  k_tc<<<dim3(FDIM/32, DDIM/64, 16), tb, 0, stream>>>(w1, w1t, w3, w3t, DDIM, FDIM);
  // w2 [E][F][D] -> [E][D][F]
  k_tc<<<dim3(DDIM/32, FDIM/64, 8), tb, 0, stream>>>(w2, w2t, w2, w2t, FDIM, DDIM);

  k_ffn1<<<dim3(FDIM/128, T_TOK/64, NEXP), 256, 0, stream>>>(xb, w1t, w3t, cnt, tok, actb);
  k_ffn2<<<dim3(DDIM/128, T_TOK/64, NEXP), 256, 0, stream>>>(actb, w2t, cnt, tok, wtb, y);
}

// Round 4
// 166.697 us; speedup vs baseline: 1.2646x; 1.2012x over previous
//
#include <hip/hip_runtime.h>
#include <hip/hip_bf16.h>
#include <stdint.h>
#include <stddef.h>

#define T_TOK 2048
#define DDIM  2048
#define FDIM  768
#define NEXP  8
#define NSLOT (T_TOK*2)

typedef __attribute__((ext_vector_type(4))) float  f32x4;
typedef __attribute__((ext_vector_type(8))) short  bf16x8;

// ---- workspace layout (bytes) ----
static constexpr size_t WS_CNT  = 0;                                  // 8 int
static constexpr size_t WS_TOK  = 256;                                // [E][T] int
static constexpr size_t WS_RTS  = WS_TOK + (size_t)NEXP*T_TOK*4;      // [T] int2
static constexpr size_t WS_WAB  = WS_RTS + (size_t)T_TOK*8;           // [T] float2
static constexpr size_t WS_XB   = WS_WAB + (size_t)T_TOK*8;           // [T][D] bf16
static constexpr size_t WS_W1T  = WS_XB  + (size_t)T_TOK*DDIM*2;      // [E][F][D] bf16
static constexpr size_t WS_W3T  = WS_W1T + (size_t)NEXP*FDIM*DDIM*2;  // [E][F][D] bf16
static constexpr size_t WS_W2T  = WS_W3T + (size_t)NEXP*FDIM*DDIM*2;  // [E][D][F] bf16
static constexpr size_t WS_ACT  = WS_W2T + (size_t)NEXP*DDIM*FDIM*2;  // [NSLOT][F] bf16
// out [NSLOT][D] bf16 (16.8MB) aliases W1T (25.2MB, dead after ffn1)
static constexpr size_t WS_OUT  = WS_W1T;

__device__ __forceinline__ void gl_lds16(const void* g, void* l) {
  __builtin_amdgcn_global_load_lds((const __attribute__((address_space(1))) void*)g,
                                   (__attribute__((address_space(3))) void*)l, 16, 0, 0);
}

__device__ __forceinline__ f32x4 mfma_bf16(bf16x8 a, bf16x8 b, f32x4 c) {
  asm("v_mfma_f32_16x16x32_bf16 %0, %1, %2, %0" : "+v"(c) : "v"(a), "v"(b));
  return c;
}

// ================= prep mega-kernel =================
// block ranges: [0,2048) router  [2048,14336) w1/w3 transpose  [14336,20480) w2 transpose
#define PREP_ROUT 2048
#define PREP_TC1  12288   // 24 x 32 x 16
#define PREP_TC2  6144    // 64 x 12 x 8
#define PREP_N    (PREP_ROUT + PREP_TC1 + PREP_TC2)

__global__ __launch_bounds__(256) void k_prep(
    const float* __restrict__ x,  const float* __restrict__ gw,
    const float* __restrict__ w1, const float* __restrict__ w2,
    const float* __restrict__ w3,
    __hip_bfloat16* __restrict__ xb,
    __hip_bfloat16* __restrict__ w1t, __hip_bfloat16* __restrict__ w2t,
    __hip_bfloat16* __restrict__ w3t,
    int* __restrict__ cnt, int* __restrict__ tok,
    int2* __restrict__ rts, float2* __restrict__ wab) {
  __shared__ float sh[64][33];
  int gid = blockIdx.x;
  int tid = threadIdx.x;

  if (gid < PREP_ROUT) {
    // ---- router + x cast: one block per token ----
    int t = gid;
    int lane = tid & 63, wave = tid >> 6;
    const float* xr = x + (size_t)t*DDIM;
    float4 x0 = *(const float4*)(xr + tid*8);
    float4 x1 = *(const float4*)(xr + tid*8 + 4);
    float xs[8] = {x0.x,x0.y,x0.z,x0.w,x1.x,x1.y,x1.z,x1.w};
    union { __hip_bfloat16 h[8]; int4 v; } pk;
    float acc[NEXP] = {0.f,0.f,0.f,0.f,0.f,0.f,0.f,0.f};
#pragma unroll
    for (int j = 0; j < 8; j++) {
      pk.h[j] = __float2bfloat16(xs[j]);
      float4 g0 = *(const float4*)(gw + (size_t)(tid*8+j)*8);
      float4 g1 = *(const float4*)(gw + (size_t)(tid*8+j)*8 + 4);
      acc[0] += xs[j]*g0.x; acc[1] += xs[j]*g0.y; acc[2] += xs[j]*g0.z; acc[3] += xs[j]*g0.w;
      acc[4] += xs[j]*g1.x; acc[5] += xs[j]*g1.y; acc[6] += xs[j]*g1.z; acc[7] += xs[j]*g1.w;
    }
    *(int4*)(xb + (size_t)t*DDIM + tid*8) = pk.v;
#pragma unroll
    for (int off = 32; off >= 1; off >>= 1) {
#pragma unroll
      for (int e = 0; e < NEXP; e++) acc[e] += __shfl_xor(acc[e], off, 64);
    }
    float* red = &sh[0][0];
    if (lane == 0) {
#pragma unroll
      for (int e = 0; e < NEXP; e++) red[wave*NEXP + e] = acc[e];
    }
    __syncthreads();
    if (tid == 0) {
      float lg[NEXP];
#pragma unroll
      for (int e = 0; e < NEXP; e++)
        lg[e] = red[e] + red[NEXP+e] + red[2*NEXP+e] + red[3*NEXP+e];
      int i1 = 0; float m1 = lg[0];
#pragma unroll
      for (int e = 1; e < NEXP; e++) if (lg[e] > m1) { m1 = lg[e]; i1 = e; }
      int i2 = -1; float m2 = -1e30f;
#pragma unroll
      for (int e = 0; e < NEXP; e++) if (e != i1 && lg[e] > m2) { m2 = lg[e]; i2 = e; }
      float r  = expf(m2 - m1);
      float wa = 1.f/(1.f + r);
      float wb = r/(1.f + r);
      int p1 = atomicAdd(&cnt[i1], 1);
      int p2 = atomicAdd(&cnt[i2], 1);
      tok[i1*T_TOK + p1] = t;
      tok[i2*T_TOK + p2] = t;
      rts[t] = make_int2((i1<<16)|p1, (i2<<16)|p2);
      wab[t] = make_float2(wa, wb);
    }
    return;
  }

  // ---- weight transpose+cast: [E][R][C] fp32 -> [E][C][R] bf16 ----
  const float* s; __hip_bfloat16* d; int R, C, bx, by;
  if (gid < PREP_ROUT + PREP_TC1) {
    int g = gid - PREP_ROUT;           // 24 x 32 x 16
    bx = g % 24; by = (g/24) % 32; int z = g/(24*32);
    R = DDIM; C = FDIM;
    s = (z < 8 ? w1 : w3) + (size_t)(z & 7)*R*C;
    d = (z < 8 ? w1t : w3t) + (size_t)(z & 7)*C*R;
  } else {
    int g = gid - PREP_ROUT - PREP_TC1; // 64 x 12 x 8
    bx = g % 64; by = (g/64) % 12; int z = g/(64*12);
    R = FDIM; C = DDIM;
    s = w2 + (size_t)z*R*C;
    d = w2t + (size_t)z*C*R;
  }
  int c0 = bx*32, r0 = by*64;
  int tx = tid & 31, ty = tid >> 5;
#pragma unroll
  for (int i = 0; i < 64; i += 8)
    sh[ty+i][tx] = s[(size_t)(r0+ty+i)*C + (c0+tx)];
  __syncthreads();
  int c  = tid >> 3;
  int rg = tid & 7;
  union { __hip_bfloat16 h[8]; int4 v; } pk;
#pragma unroll
  for (int j = 0; j < 8; j++) pk.h[j] = __float2bfloat16(sh[rg*8+j][c]);
  *(int4*)(d + (size_t)(c0+c)*R + r0 + rg*8) = pk.v;
}

// ================= phase 1: g=Xe@W1, u=Xe@W3, act=silu(g)*u =================
// BM=64, BN=128, BK=64; 4 waves 2x2; dbuf LDS; counted-vmcnt raw barriers (T4).
__global__ __launch_bounds__(256,2) void k_ffn1(
    const __hip_bfloat16* __restrict__ xb,
    const __hip_bfloat16* __restrict__ w1t,   // [E][F][D]
    const __hip_bfloat16* __restrict__ w3t,   // [E][F][D]
    const int* __restrict__ cnt,
    const int* __restrict__ tok,
    __hip_bfloat16* __restrict__ act) {       // [NSLOT][F]
  int e  = blockIdx.z;
  int ne = cnt[e];
  int m0 = blockIdx.y * 64;
  if (m0 >= ne) return;
  int n0 = blockIdx.x * 128;
  int tid = threadIdx.x, wave = tid >> 6, lane = tid & 63;

  __shared__ __hip_bfloat16 sA[2][64*64], sB1[2][128*64], sB3[2][128*64]; // 80 KB

  const __hip_bfloat16 *aptr[2], *b1p[4], *b3p[4];
  int ldsA[2], ldsB[4];
#pragma unroll
  for (int c = 0; c < 2; c++) {
    int r  = c*32 + wave*8 + (lane>>3);
    int kb = ((lane&7)*16) ^ ((r&7)<<4);
    int slot = m0 + r; if (slot >= ne) slot = ne - 1;
    int t = tok[e*T_TOK + slot];
    aptr[c] = xb + (size_t)t*DDIM + (kb>>1);
    ldsA[c] = (c*32 + wave*8)*128;
  }
#pragma unroll
  for (int c = 0; c < 4; c++) {
    int r  = c*32 + wave*8 + (lane>>3);
    int kb = ((lane&7)*16) ^ ((r&7)<<4);
    b1p[c] = w1t + ((size_t)e*FDIM + n0 + r)*DDIM + (kb>>1);
    b3p[c] = w3t + ((size_t)e*FDIM + n0 + r)*DDIM + (kb>>1);
    ldsB[c] = (c*32 + wave*8)*128;
  }

  f32x4 accg[2][4], accu[2][4];
#pragma unroll
  for (int a = 0; a < 2; a++)
#pragma unroll
    for (int b = 0; b < 4; b++) {
      accg[a][b] = (f32x4){0.f,0.f,0.f,0.f};
      accu[a][b] = (f32x4){0.f,0.f,0.f,0.f};
    }

  int wr = wave >> 1, wc = wave & 1;

#define FFN1_STAGE(B, KT) do { \
  _Pragma("unroll") for (int c = 0; c < 2; c++) \
    gl_lds16(aptr[c] + (KT)*64, (char*)&sA[B][0]  + ldsA[c]); \
  _Pragma("unroll") for (int c = 0; c < 4; c++) { \
    gl_lds16(b1p[c]  + (KT)*64, (char*)&sB1[B][0] + ldsB[c]); \
    gl_lds16(b3p[c]  + (KT)*64, (char*)&sB3[B][0] + ldsB[c]); } \
} while (0)

#define FFN1_COMP(B) do { \
  _Pragma("unroll") for (int ks = 0; ks < 2; ks++) { \
    int q = ks*64 + ((lane>>4)<<4); \
    bf16x8 a_[2], b1_[4], b3_[4]; \
    _Pragma("unroll") for (int mf = 0; mf < 2; mf++) { \
      int r = wr*32 + mf*16 + (lane&15); \
      a_[mf] = *(const bf16x8*)((const char*)&sA[B][0] + r*128 + (q ^ ((r&7)<<4))); } \
    _Pragma("unroll") for (int nf = 0; nf < 4; nf++) { \
      int r = wc*64 + nf*16 + (lane&15); \
      int off = r*128 + (q ^ ((r&7)<<4)); \
      b1_[nf] = *(const bf16x8*)((const char*)&sB1[B][0] + off); \
      b3_[nf] = *(const bf16x8*)((const char*)&sB3[B][0] + off); } \
    _Pragma("unroll") for (int mf = 0; mf < 2; mf++) \
      _Pragma("unroll") for (int nf = 0; nf < 4; nf++) { \
        accg[mf][nf] = mfma_bf16(a_[mf], b1_[nf], accg[mf][nf]); \
        accu[mf][nf] = mfma_bf16(a_[mf], b3_[nf], accu[mf][nf]); } \
  } \
} while (0)

  const int NK = DDIM/64;   // 32
  FFN1_STAGE(0, 0);
  for (int kt = 0; kt < NK; ++kt) {
    int cur = kt & 1;
    if (kt + 1 < NK) {
      FFN1_STAGE(cur^1, kt+1);
      asm volatile("s_waitcnt vmcnt(10)" ::: "memory");  // 10 newest in flight
    } else {
      asm volatile("s_waitcnt vmcnt(0)" ::: "memory");
    }
    __builtin_amdgcn_s_barrier();
    FFN1_COMP(cur);
    __builtin_amdgcn_s_barrier();
  }

  int be = 0;
#pragma unroll
  for (int i = 0; i < NEXP; i++) if (i < e) be += cnt[i];
#pragma unroll
  for (int mf = 0; mf < 2; mf++)
#pragma unroll
    for (int nf = 0; nf < 4; nf++)
#pragma unroll
      for (int j = 0; j < 4; j++) {
        int slot = m0 + wr*32 + mf*16 + (lane>>4)*4 + j;  // C/D: row=(lane>>4)*4+j
        if (slot < ne) {
          int f = n0 + wc*64 + nf*16 + (lane&15);         // C/D: col=lane&15
          float g = accg[mf][nf][j], u = accu[mf][nf][j];
          float s = g / (1.f + __expf(-g));
          act[(size_t)(be+slot)*FDIM + f] = __float2bfloat16(s*u);
        }
      }
}

// ================= phase 2: out[slot] = act@W2 (NO atomics) =================
__global__ __launch_bounds__(256,3) void k_ffn2(
    const __hip_bfloat16* __restrict__ act,   // [NSLOT][F]
    const __hip_bfloat16* __restrict__ w2t,   // [E][D][F]
    const int* __restrict__ cnt,
    __hip_bfloat16* __restrict__ out) {       // [NSLOT][D]
  int e  = blockIdx.z;
  int ne = cnt[e];
  int m0 = blockIdx.y * 64;
  if (m0 >= ne) return;
  int n0 = blockIdx.x * 128;
  int tid = threadIdx.x, wave = tid >> 6, lane = tid & 63;
  int be = 0;
#pragma unroll
  for (int i = 0; i < NEXP; i++) if (i < e) be += cnt[i];

  __shared__ __hip_bfloat16 sA[2][64*64], sB[2][128*64];  // 48 KB

  const __hip_bfloat16 *aptr[2], *bp[4];
  int ldsA[2], ldsB[4];
#pragma unroll
  for (int c = 0; c < 2; c++) {
    int r  = c*32 + wave*8 + (lane>>3);
    int kb = ((lane&7)*16) ^ ((r&7)<<4);
    int slot = m0 + r; if (slot >= ne) slot = ne - 1;
    aptr[c] = act + (size_t)(be+slot)*FDIM + (kb>>1);
    ldsA[c] = (c*32 + wave*8)*128;
  }
#pragma unroll
  for (int c = 0; c < 4; c++) {
    int r  = c*32 + wave*8 + (lane>>3);
    int kb = ((lane&7)*16) ^ ((r&7)<<4);
    bp[c]  = w2t + ((size_t)e*DDIM + n0 + r)*FDIM + (kb>>1);
    ldsB[c] = (c*32 + wave*8)*128;
  }

  f32x4 acc[2][4];
#pragma unroll
  for (int a = 0; a < 2; a++)
#pragma unroll
    for (int b = 0; b < 4; b++) acc[a][b] = (f32x4){0.f,0.f,0.f,0.f};

  int wr = wave >> 1, wc = wave & 1;

#define FFN2_STAGE(B, KT) do { \
  _Pragma("unroll") for (int c = 0; c < 2; c++) \
    gl_lds16(aptr[c] + (KT)*64, (char*)&sA[B][0] + ldsA[c]); \
  _Pragma("unroll") for (int c = 0; c < 4; c++) \
    gl_lds16(bp[c]   + (KT)*64, (char*)&sB[B][0] + ldsB[c]); \
} while (0)

#define FFN2_COMP(B) do { \
  _Pragma("unroll") for (int ks = 0; ks < 2; ks++) { \
    int q = ks*64 + ((lane>>4)<<4); \
    bf16x8 a_[2], b_[4]; \
    _Pragma("unroll") for (int mf = 0; mf < 2; mf++) { \
      int r = wr*32 + mf*16 + (lane&15); \
      a_[mf] = *(const bf16x8*)((const char*)&sA[B][0] + r*128 + (q ^ ((r&7)<<4))); } \
    _Pragma("unroll") for (int nf = 0; nf < 4; nf++) { \
      int r = wc*64 + nf*16 + (lane&15); \
      b_[nf] = *(const bf16x8*)((const char*)&sB[B][0] + r*128 + (q ^ ((r&7)<<4))); } \
    _Pragma("unroll") for (int mf = 0; mf < 2; mf++) \
      _Pragma("unroll") for (int nf = 0; nf < 4; nf++) \
        acc[mf][nf] = mfma_bf16(a_[mf], b_[nf], acc[mf][nf]); \
  } \
} while (0)

  const int NK = FDIM/64;   // 12
  FFN2_STAGE(0, 0);
  for (int kt = 0; kt < NK; ++kt) {
    int cur = kt & 1;
    if (kt + 1 < NK) {
      FFN2_STAGE(cur^1, kt+1);
      asm volatile("s_waitcnt vmcnt(6)" ::: "memory");   // 6 newest in flight
    } else {
      asm volatile("s_waitcnt vmcnt(0)" ::: "memory");
    }
    __builtin_amdgcn_s_barrier();
    FFN2_COMP(cur);
    __builtin_amdgcn_s_barrier();
  }

#pragma unroll
  for (int mf = 0; mf < 2; mf++)
#pragma unroll
    for (int nf = 0; nf < 4; nf++)
#pragma unroll
      for (int j = 0; j < 4; j++) {
        int slot = m0 + wr*32 + mf*16 + (lane>>4)*4 + j;
        if (slot < ne) {
          int d = n0 + wc*64 + nf*16 + (lane&15);
          out[(size_t)(be+slot)*DDIM + d] = __float2bfloat16(acc[mf][nf][j]);
        }
      }
}

// ================= combine: y[t] = wa*out[sa] + wb*out[sb] =================
__global__ __launch_bounds__(256) void k_combine(
    const __hip_bfloat16* __restrict__ out,   // [NSLOT][D]
    const int2* __restrict__ rts, const float2* __restrict__ wab,
    const int* __restrict__ cnt,
    float* __restrict__ y) {
  int t = blockIdx.x;
  int tid = threadIdx.x;
  int2  r = rts[t];
  float2 w = wab[t];
  int i1 = r.x >> 16, p1 = r.x & 0xFFFF;
  int i2 = r.y >> 16, p2 = r.y & 0xFFFF;
  int sa = p1, sb = p2;
#pragma unroll
  for (int e = 0; e < NEXP; e++) {
    int c = cnt[e];
    if (e < i1) sa += c;
    if (e < i2) sb += c;
  }
  union { bf16x8 v; __hip_bfloat16 h[8]; } ua, ub;
  ua.v = *(const bf16x8*)(out + (size_t)sa*DDIM + tid*8);
  ub.v = *(const bf16x8*)(out + (size_t)sb*DDIM + tid*8);
  float4 o0, o1;
  float* o = &o0.x;
#pragma unroll
  for (int j = 0; j < 4; j++)
    (&o0.x)[j] = w.x*__bfloat162float(ua.h[j]) + w.y*__bfloat162float(ub.h[j]);
#pragma unroll
  for (int j = 0; j < 4; j++)
    (&o1.x)[j] = w.x*__bfloat162float(ua.h[4+j]) + w.y*__bfloat162float(ub.h[4+j]);
  (void)o;
  float* yr = y + (size_t)t*DDIM + tid*8;
  *(float4*)(yr)     = o0;
  *(float4*)(yr + 4) = o1;
}

extern "C" void kernel_launch(void* const* d_in, const int* in_sizes, int n_in,
                              void* d_out, int out_size, void* d_ws, size_t ws_size,
                              hipStream_t stream) {
  const float* x  = (const float*)d_in[0];
  const float* gw = (const float*)d_in[1];
  const float* w1 = (const float*)d_in[2];
  const float* w2 = (const float*)d_in[3];
  const float* w3 = (const float*)d_in[4];
  float* y = (float*)d_out;
  char* ws = (char*)d_ws;

  int*    cnt  = (int*)   (ws + WS_CNT);
  int*    tok  = (int*)   (ws + WS_TOK);
  int2*   rts  = (int2*)  (ws + WS_RTS);
  float2* wab  = (float2*)(ws + WS_WAB);
  __hip_bfloat16* xb   = (__hip_bfloat16*)(ws + WS_XB);
  __hip_bfloat16* w1t  = (__hip_bfloat16*)(ws + WS_W1T);
  __hip_bfloat16* w3t  = (__hip_bfloat16*)(ws + WS_W3T);
  __hip_bfloat16* w2t  = (__hip_bfloat16*)(ws + WS_W2T);
  __hip_bfloat16* actb = (__hip_bfloat16*)(ws + WS_ACT);
  __hip_bfloat16* outb = (__hip_bfloat16*)(ws + WS_OUT);

  hipMemsetAsync(ws + WS_CNT, 0, 256, stream);

  k_prep<<<PREP_N, 256, 0, stream>>>(x, gw, w1, w2, w3, xb, w1t, w2t, w3t,
                                     cnt, tok, rts, wab);

  k_ffn1<<<dim3(FDIM/128, T_TOK/64, NEXP), 256, 0, stream>>>(xb, w1t, w3t, cnt, tok, actb);
  k_ffn2<<<dim3(DDIM/128, T_TOK/64, NEXP), 256, 0, stream>>>(actb, w2t, cnt, outb);
  k_combine<<<T_TOK, 256, 0, stream>>>(outb, rts, wab, cnt, y);
}